// Round 4
// baseline (1608.575 us; speedup 1.0000x reference)
//
#include <hip/hip_runtime.h>

// ============================================================================
// Bidirectional LSTM encoder, MI355X.  R4: tag-in-data sync, group-of-8.
//   - publish: dword = (bf16_h << 16) | step_tag. Readers retry until tags
//     match s-1. No flags, no producer vmcnt-ack, no separate poll.
//   - 2 groups (fwd/bwd) x 8 wgs; each wg: 256 z-cols, U-slice = 128 VGPRs.
//   - in-wave gates via quad 4x4 transpose (shfl_xor); 2 barriers/step.
//   - double-buffered LDS stage; replay-safe via prep-time tag clears.
// ============================================================================

typedef unsigned short u16;
typedef unsigned int   u32;
typedef u16   u16x8 __attribute__((ext_vector_type(8)));
typedef u16   u16x4 __attribute__((ext_vector_type(4)));
typedef u32   u32x4 __attribute__((ext_vector_type(4)));
typedef u32   u32x2 __attribute__((ext_vector_type(2)));
typedef __bf16 bf16x8 __attribute__((ext_vector_type(8)));
typedef float f32x4 __attribute__((ext_vector_type(4)));

#define EP 320            // padded E (300 -> 320)
#define NC 4096           // 2 dirs * 4H

static const size_t OFF_AEMB = 0;                              // 8192*320*2
static const size_t OFF_WPT  = OFF_AEMB + (size_t)8192*EP*2;
static const size_t OFF_BIAS = OFF_WPT  + (size_t)NC*EP*2;     // f32[4096]
static const size_t OFF_UPT  = OFF_BIAS + (size_t)NC*4;        // bf16 [4096][512]
static const size_t OFF_MASK = OFF_UPT  + (size_t)NC*512*2;    // u32 [32][8]
static const size_t OFF_HIMG = OFF_MASK + 1024;                // u32 2dir*2par*16384 dwords
static const size_t OFF_XW   = OFF_HIMG + (size_t)2*2*16384*4; // bf16 [8192][4096]

__device__ __forceinline__ u16 f2bf(float f){               // RNE
  u32 u = __builtin_bit_cast(u32, f);
  return (u16)((u + 0x7FFFu + ((u >> 16) & 1u)) >> 16);
}
__device__ __forceinline__ float bf2f(u16 h){
  u32 u = ((u32)h) << 16; return __builtin_bit_cast(float, u);
}
__device__ __forceinline__ float sigm(float x){ return 1.f/(1.f+__expf(-x)); }
__device__ __forceinline__ float tanh_(float x){ return 2.f/(1.f+__expf(-2.f*x)) - 1.f; }

// ---------------------------------------------------------------- prep: A=emb gather
__global__ __launch_bounds__(320) void k_prep_aemb(const int* __restrict__ x,
                                                   const float* __restrict__ emb,
                                                   u16* __restrict__ aemb){
  int m = blockIdx.x;            // row = t*32 + b
  int k = threadIdx.x;
  int b = m & 31, t = m >> 5;
  int tok = x[b*256 + t];
  float v = (k < 300) ? emb[(size_t)tok*300 + k] : 0.f;
  aemb[(size_t)m*EP + k] = f2bf(v);
}

// ---------------------------------------------------------------- prep: W -> [col'][K] bf16 + bias
__global__ __launch_bounds__(256) void k_prep_wt(const float* __restrict__ Wf, const float* __restrict__ Wb,
                                                 const float* __restrict__ bfv, const float* __restrict__ bbv,
                                                 u16* __restrict__ wpt, float* __restrict__ bias){
  __shared__ u16 lds[320][64];
  int bid = blockIdx.x, tid = threadIdx.x;   // 64 wgs
  int c0 = bid*64; int dir = c0 >> 11;
  const float* W = dir ? Wb : Wf;
  int cl = tid & 63, rr = tid >> 6;
  int ci = (c0 + cl) & 2047; int srccol = (ci & 3)*512 + (ci >> 2);   // col' = u*4+g  <- g*512+u
  for (int kk = 0; kk < 80; kk++){
    int row = kk*4 + rr;
    float v = (row < 300) ? W[(size_t)row*2048 + srccol] : 0.f;
    lds[row][cl] = f2bf(v);
  }
  __syncthreads();
  int cw = tid >> 2, kc = tid & 3;
  #pragma unroll
  for (int j = 0; j < 10; j++){
    u16x8 v;
    #pragma unroll
    for (int e = 0; e < 8; e++) v[e] = lds[kc*80 + j*8 + e][cw];
    *(u16x8*)&wpt[(size_t)(c0+cw)*EP + kc*80 + j*8] = v;
  }
  if (tid < 64){
    int ci2 = (c0 + tid) & 2047; int sc = (ci2 & 3)*512 + (ci2 >> 2);
    bias[c0 + tid] = (dir ? bbv : bfv)[sc];
  }
}

// ---------------------------------------------------------------- prep: U -> [col'][K] bf16
__global__ __launch_bounds__(256) void k_prep_ut(const float* __restrict__ Uf, const float* __restrict__ Ub,
                                                 u16* __restrict__ upt){
  __shared__ u16 lds[512][32];
  int bid = blockIdx.x, tid = threadIdx.x;   // 128 wgs
  int cg0 = bid*32; int dir = cg0 >> 11;
  const float* U = dir ? Ub : Uf;
  int cl = tid & 31, rr = tid >> 5;
  int ci = (cg0 + cl) & 2047; int srccol = (ci & 3)*512 + (ci >> 2);
  for (int kk = 0; kk < 64; kk++){
    int row = kk*8 + rr;
    lds[row][cl] = f2bf(U[(size_t)row*2048 + srccol]);
  }
  __syncthreads();
  int cw = tid >> 3, kc = tid & 7;
  #pragma unroll
  for (int j = 0; j < 8; j++){
    u16x8 v;
    #pragma unroll
    for (int e = 0; e < 8; e++) v[e] = lds[kc*64 + j*8 + e][cw];
    *(u16x8*)&upt[(size_t)(cg0+cw)*512 + kc*64 + j*8] = v;
  }
}

// ---------------------------------------------------------------- prep: mask + tagged h image init
__global__ __launch_bounds__(256) void k_prep_misc(const int* __restrict__ x,
                                                   const float* __restrict__ h0f, const float* __restrict__ h0b,
                                                   u32* __restrict__ maskb, u32* __restrict__ himg){
  int bid = blockIdx.x, tid = threadIdx.x;
  if (bid == 256){
    int b = tid >> 3, w = tid & 7;
    u32 m = 0;
    for (int i = 0; i < 32; i++){ int t = w*32 + i; m |= (u32)(x[b*256 + t] != 0) << i; }
    maskb[b*8 + w] = m;
    return;
  }
  int idx = bid*256 + tid;                      // 0 .. 65535
  int dir = idx >> 15, rem = idx & 32767, par = rem >> 14, di = rem & 16383;
  u32* img = himg + (size_t)dir*32768 + (size_t)par*16384;
  if (par == 0){
    img[di] = 0x0000DEADu;                      // invalid tag (never matches 0..254 / 0xFFFF)
  } else {
    int j = di & 7, lane2 = (di >> 3) & 63, ks = (di >> 9) & 15, mt = di >> 13;
    int b = mt*16 + (lane2 & 15), ug = ks*32 + (lane2 >> 4)*8 + j;
    const float* h0 = dir ? h0b : h0f;
    img[di] = ((u32)f2bf(h0[b*512 + ug]) << 16) | 0xFFFFu;   // h_{-1}, tag -1
  }
}

// ---------------------------------------------------------------- input GEMM: xW+b (bf16 MFMA)
__global__ __launch_bounds__(512) void k_ingemm(const u16* __restrict__ aemb, const u16* __restrict__ wpt,
                                                const float* __restrict__ bias, u16* __restrict__ xw){
  int bx = blockIdx.x, by = blockIdx.y;        // 64 x 64
  int tid = threadIdx.x, lane = tid & 63, wv = tid >> 6;
  int m0 = bx*128 + wv*16;
  u16x8 afr[10];
  const u16* ap = aemb + (size_t)(m0 + (lane & 15))*EP + ((lane >> 4)*8);
  #pragma unroll
  for (int ks = 0; ks < 10; ks++) afr[ks] = *(const u16x8*)(ap + ks*32);
  #pragma unroll
  for (int n = 0; n < 4; n++){
    int colp = by*64 + n*16 + (lane & 15);
    const u16* bp = wpt + (size_t)colp*EP + ((lane >> 4)*8);
    f32x4 acc = {0.f, 0.f, 0.f, 0.f};
    #pragma unroll
    for (int ks = 0; ks < 10; ks++){
      bf16x8 bfr = __builtin_bit_cast(bf16x8, *(const u16x8*)(bp + ks*32));
      acc = __builtin_amdgcn_mfma_f32_16x16x32_bf16(__builtin_bit_cast(bf16x8, afr[ks]), bfr, acc, 0, 0, 0);
    }
    float bv = bias[colp];
    #pragma unroll
    for (int v = 0; v < 4; v++){
      int m = m0 + (lane >> 4)*4 + v;          // C/D: col=lane&15, row=(lane>>4)*4+reg  [m89]
      xw[(size_t)m*NC + colp] = f2bf(acc[v] + bv);
    }
  }
}

// ---------------------------------------------------------------- persistent recurrence
__global__ __launch_bounds__(512) void k_recur(const u16* __restrict__ xw, const u16* __restrict__ upt,
                                               const u32* __restrict__ maskb, u32* __restrict__ himg,
                                               const float* __restrict__ c0f, const float* __restrict__ c0b,
                                               const float* __restrict__ h0f, const float* __restrict__ h0b,
                                               float* __restrict__ out){
  int bid = blockIdx.x;                        // 16 wgs
  int dir = bid & 1, r = bid >> 1;             // direction, rank in group (0..7)
  int tid = threadIdx.x, lane = tid & 63, wv = tid >> 6;

  __shared__ u16 astage[2][16384];             // double-buffered bf16 frag image (64 KB)
  __shared__ u16 hpub[2048];                   // publish tile (4 KB)
  __shared__ u32 mk[32][8];

  // U-slice as persistent B-fragments: cols r*256 + wv*32 + n*16 + (lane&15), full K
  bf16x8 bfr[2][16];
  #pragma unroll
  for (int n = 0; n < 2; n++){
    const u16* ub = upt + ((size_t)dir*2048 + r*256 + wv*32 + n*16 + (lane & 15))*512 + ((lane >> 4)*8);
    #pragma unroll
    for (int ks = 0; ks < 16; ks++)
      bfr[n][ks] = __builtin_bit_cast(bf16x8, *(const u16x8*)(ub + ks*32));
  }

  int bq = (lane >> 4)*4 + (lane & 3);         // post-transpose batch row (0..15)
  int u2 = (lane & 15) >> 2;                   // unit-within-quad
  const float* c0 = dir ? c0b : c0f;
  const float* h0 = dir ? h0b : h0f;
  float cst[2][2], hst[2][2];
  #pragma unroll
  for (int m = 0; m < 2; m++)
    #pragma unroll
    for (int n = 0; n < 2; n++){
      int b = m*16 + bq, ug = r*64 + wv*8 + n*4 + u2;
      cst[m][n] = c0[b*512 + ug];
      hst[m][n] = h0[b*512 + ug];
    }
  if (tid < 256) mk[tid >> 3][tid & 7] = maskb[tid];
  __syncthreads();

  u32* img = himg + (size_t)dir*32768;

  int t0 = dir ? 255 : 0;
  u16x4 pref[2][2];
  #pragma unroll
  for (int m = 0; m < 2; m++)
    #pragma unroll
    for (int n = 0; n < 2; n++)
      pref[m][n] = *(const u16x4*)(xw + (size_t)(t0*32 + m*16 + bq)*NC + dir*2048 + (r*64 + wv*8 + n*4 + u2)*4);

  for (int s = 0; s < 256; ++s){
    int t = dir ? 255 - s : s;
    int sn = (s < 255) ? s + 1 : s;
    int tn = dir ? 255 - sn : sn;
    u16x4 nxt[2][2];
    #pragma unroll
    for (int m = 0; m < 2; m++)
      #pragma unroll
      for (int n = 0; n < 2; n++)
        nxt[m][n] = *(const u16x4*)(xw + (size_t)(tn*32 + m*16 + bq)*NC + dir*2048 + (r*64 + wv*8 + n*4 + u2)*4);

    // ---- stage + verify: 8 x dwordx4 coherent loads, retry until tags == s-1
    u32 tg = (u32)((s - 1) & 0xFFFF);
    int pr = (s + 1) & 1;
    const char* gsrc = (const char*)(img + (size_t)pr*16384) + (size_t)tid*16;
    u32x4 v0, v1, v2, v3, v4, v5, v6, v7;
    #define LD(i) asm volatile("global_load_dwordx4 %0, %1, off sc0 sc1" : "=v"(v##i) : "v"(gsrc + i*8192))
    LD(0); LD(1); LD(2); LD(3); LD(4); LD(5); LD(6); LD(7);
    u32 pend = 255u;
    for (;;){
      asm volatile("s_waitcnt vmcnt(0)" ::: "memory");
      __builtin_amdgcn_sched_barrier(0);
      #define CK(i) if (pend & (1u << i)){ \
        if ((((v##i.x ^ tg) | (v##i.y ^ tg) | (v##i.z ^ tg) | (v##i.w ^ tg)) & 0xFFFFu) == 0u){ \
          u32x2 p; p.x = (v##i.x >> 16) | (v##i.y & 0xFFFF0000u); \
                   p.y = (v##i.z >> 16) | (v##i.w & 0xFFFF0000u); \
          *(u32x2*)((char*)&astage[pr][0] + i*4096 + (size_t)tid*8) = p; \
          pend &= ~(1u << i); \
        } else { LD(i); } }
      CK(0); CK(1); CK(2); CK(3); CK(4); CK(5); CK(6); CK(7);
      #undef CK
      if (!pend) break;
    }
    #undef LD
    __syncthreads();                            // (B) astage[pr] ready

    // ---- z = h_{s-1} @ U, full K per wave
    f32x4 acc[2][2] = {{{0.f,0.f,0.f,0.f},{0.f,0.f,0.f,0.f}},{{0.f,0.f,0.f,0.f},{0.f,0.f,0.f,0.f}}};
    {
      const u16* ab = &astage[pr][0] + lane*8;
      #pragma unroll
      for (int ks = 0; ks < 16; ks++){
        bf16x8 a0 = __builtin_bit_cast(bf16x8, *(const u16x8*)(ab + ks*512));
        bf16x8 a1 = __builtin_bit_cast(bf16x8, *(const u16x8*)(ab + (16 + ks)*512));
        acc[0][0] = __builtin_amdgcn_mfma_f32_16x16x32_bf16(a0, bfr[0][ks], acc[0][0], 0, 0, 0);
        acc[0][1] = __builtin_amdgcn_mfma_f32_16x16x32_bf16(a0, bfr[1][ks], acc[0][1], 0, 0, 0);
        acc[1][0] = __builtin_amdgcn_mfma_f32_16x16x32_bf16(a1, bfr[0][ks], acc[1][0], 0, 0, 0);
        acc[1][1] = __builtin_amdgcn_mfma_f32_16x16x32_bf16(a1, bfr[1][ks], acc[1][1], 0, 0, 0);
      }
    }

    // ---- quad 4x4 transpose + gates, all in-wave
    bool sel0 = (lane & 1), sel1 = (lane & 2);
    #pragma unroll
    for (int m = 0; m < 2; m++){
      int b = m*16 + bq;
      u32 mbit = (mk[b][t >> 5] >> (t & 31)) & 1u;
      #pragma unroll
      for (int n = 0; n < 2; n++){
        f32x4 a = acc[m][n], tt, rr, t2, o;
        #pragma unroll
        for (int e = 0; e < 4; e++) tt[e] = __shfl_xor(a[e], 1);
        rr[0] = sel0 ? tt[1] : a[0];  rr[1] = sel0 ? a[1] : tt[0];
        rr[2] = sel0 ? tt[3] : a[2];  rr[3] = sel0 ? a[3] : tt[2];
        #pragma unroll
        for (int e = 0; e < 4; e++) t2[e] = __shfl_xor(rr[e], 2);
        o[0] = sel1 ? t2[2] : rr[0];  o[1] = sel1 ? t2[3] : rr[1];
        o[2] = sel1 ? rr[2] : t2[0];  o[3] = sel1 ? rr[3] : t2[1];

        float zi = o[0] + bf2f(pref[m][n][0]);
        float zf = o[1] + bf2f(pref[m][n][1]);
        float zg = o[2] + bf2f(pref[m][n][2]);
        float zo = o[3] + bf2f(pref[m][n][3]);
        float gi = sigm(zi), gf = sigm(zf), gg = tanh_(zg), go = sigm(zo);
        float cn = gf*cst[m][n] + gi*gg;
        float hn = go*tanh_(cn);
        if (mbit){ cst[m][n] = cn; hst[m][n] = hn; }
        float hc = hst[m][n];

        int ug = r*64 + wv*8 + n*4 + u2;
        hpub[((m*2 + (wv >> 2))*64 + (wv & 3)*16 + bq)*8 + n*4 + u2] = f2bf(hc);
        out[(size_t)(b*256 + t)*1024 + dir*512 + ug] = hc;
        if (s == 255){
          out[8388608 + dir*16384 + b*512 + ug] = hc;
          out[8388608 + 32768 + dir*16384 + b*512 + ug] = cst[m][n];
        }
        pref[m][n] = nxt[m][n];
      }
    }
    __syncthreads();                            // (D) hpub ready

    // ---- publish h_s: each thread 1 tagged dwordx4 (fire-and-forget)
    if (s < 255){
      int mt = tid >> 8, ksl = (tid >> 7) & 1, lane2 = (tid >> 1) & 63, j0 = (tid & 1)*4;
      u16x4 hv = *(const u16x4*)&hpub[tid*4];
      u32 tgp = (u32)s;
      u32x4 dw;
      dw.x = ((u32)hv[0] << 16) | tgp;  dw.y = ((u32)hv[1] << 16) | tgp;
      dw.z = ((u32)hv[2] << 16) | tgp;  dw.w = ((u32)hv[3] << 16) | tgp;
      u32* gdst = img + (size_t)(s & 1)*16384 + ((size_t)((mt*16 + r*2 + ksl)*64 + lane2)*8 + j0);
      asm volatile("global_store_dwordx4 %0, %1, off sc0 sc1" :: "v"(gdst), "v"(dw) : "memory");
    }
  }
}

// ----------------------------------------------------------------------------
extern "C" void kernel_launch(void* const* d_in, const int* in_sizes, int n_in,
                              void* d_out, int out_size, void* d_ws, size_t ws_size,
                              hipStream_t stream){
  const int*   x   = (const int*)  d_in[0];
  const float* h0f = (const float*)d_in[1];
  const float* c0f = (const float*)d_in[2];
  const float* h0b = (const float*)d_in[3];
  const float* c0b = (const float*)d_in[4];
  const float* emb = (const float*)d_in[5];
  const float* Wf  = (const float*)d_in[6];
  const float* Uf  = (const float*)d_in[7];
  const float* bfv = (const float*)d_in[8];
  const float* Wb  = (const float*)d_in[9];
  const float* Ub  = (const float*)d_in[10];
  const float* bbv = (const float*)d_in[11];
  float* out = (float*)d_out;

  char* w = (char*)d_ws;
  u16*   aemb = (u16*)(w + OFF_AEMB);
  u16*   wpt  = (u16*)(w + OFF_WPT);
  float* bias = (float*)(w + OFF_BIAS);
  u16*   upt  = (u16*)(w + OFF_UPT);
  u32*   mskb = (u32*)(w + OFF_MASK);
  u32*   himg = (u32*)(w + OFF_HIMG);
  u16*   xw   = (u16*)(w + OFF_XW);

  k_prep_aemb<<<dim3(8192),  dim3(320), 0, stream>>>(x, emb, aemb);
  k_prep_wt  <<<dim3(64),    dim3(256), 0, stream>>>(Wf, Wb, bfv, bbv, wpt, bias);
  k_prep_ut  <<<dim3(128),   dim3(256), 0, stream>>>(Uf, Ub, upt);
  k_prep_misc<<<dim3(257),   dim3(256), 0, stream>>>(x, h0f, h0b, mskb, himg);
  k_ingemm   <<<dim3(64,64), dim3(512), 0, stream>>>(aemb, wpt, bias, xw);
  k_recur    <<<dim3(16),    dim3(512), 0, stream>>>(xw, upt, mskb, himg,
                                                     c0f, c0b, h0f, h0b, out);
}

// Round 6
// 971.719 us; speedup vs baseline: 1.6554x; 1.6554x over previous
//
#include <hip/hip_runtime.h>

// ============================================================================
// Bidirectional LSTM encoder, MI355X.  R6: R5 with corrected 8-chunk reader.
//   - 2 groups (fwd/bwd) x 32 wgs (64 z-cols/wg, B-frags = 32 VGPRs, no spill).
//   - publish: each gate thread stores its own h as (bf16<<16 | step) dword,
//     immediately after gate math. No flags, no ack, no publish barrier.
//   - readers: 8 tagged 16B chunks/thread (full 64KB parity image), per-chunk
//     verify+retry, pack bf16 to LDS on verify. 2 barriers/step.
//   - distance-2 WAR safety at chunk granularity; replay-safe via prep re-init.
// ============================================================================

typedef unsigned short u16;
typedef unsigned int   u32;
typedef u16   u16x8 __attribute__((ext_vector_type(8)));
typedef u16   u16x4 __attribute__((ext_vector_type(4)));
typedef u32   u32x4 __attribute__((ext_vector_type(4)));
typedef __bf16 bf16x8 __attribute__((ext_vector_type(8)));
typedef float f32x4 __attribute__((ext_vector_type(4)));

#define EP 320            // padded E (300 -> 320)
#define NC 4096           // 2 dirs * 4H

static const size_t OFF_AEMB = 0;                              // 8192*320*2
static const size_t OFF_WPT  = OFF_AEMB + (size_t)8192*EP*2;
static const size_t OFF_BIAS = OFF_WPT  + (size_t)NC*EP*2;     // f32[4096]
static const size_t OFF_UPT  = OFF_BIAS + (size_t)NC*4;        // bf16 [4096][512]
static const size_t OFF_MASK = OFF_UPT  + (size_t)NC*512*2;    // u32 [32][8]
static const size_t OFF_HIMG = OFF_MASK + 1024;                // u32 2dir*2par*16384 dwords
static const size_t OFF_XW   = OFF_HIMG + (size_t)2*2*16384*4; // bf16 [8192][4096]

__device__ __forceinline__ u16 f2bf(float f){               // RNE
  u32 u = __builtin_bit_cast(u32, f);
  return (u16)((u + 0x7FFFu + ((u >> 16) & 1u)) >> 16);
}
__device__ __forceinline__ float bf2f(u16 h){
  u32 u = ((u32)h) << 16; return __builtin_bit_cast(float, u);
}
__device__ __forceinline__ float sigm(float x){ return 1.f/(1.f+__expf(-x)); }
__device__ __forceinline__ float tanh_(float x){ return 2.f/(1.f+__expf(-2.f*x)) - 1.f; }

// ---------------------------------------------------------------- prep: A=emb gather
__global__ __launch_bounds__(320) void k_prep_aemb(const int* __restrict__ x,
                                                   const float* __restrict__ emb,
                                                   u16* __restrict__ aemb){
  int m = blockIdx.x;            // row = t*32 + b
  int k = threadIdx.x;
  int b = m & 31, t = m >> 5;
  int tok = x[b*256 + t];
  float v = (k < 300) ? emb[(size_t)tok*300 + k] : 0.f;
  aemb[(size_t)m*EP + k] = f2bf(v);
}

// ---------------------------------------------------------------- prep: W -> [col'][K] bf16 + bias
__global__ __launch_bounds__(256) void k_prep_wt(const float* __restrict__ Wf, const float* __restrict__ Wb,
                                                 const float* __restrict__ bfv, const float* __restrict__ bbv,
                                                 u16* __restrict__ wpt, float* __restrict__ bias){
  __shared__ u16 lds[320][64];
  int bid = blockIdx.x, tid = threadIdx.x;   // 64 wgs
  int c0 = bid*64; int dir = c0 >> 11;
  const float* W = dir ? Wb : Wf;
  int cl = tid & 63, rr = tid >> 6;
  int ci = (c0 + cl) & 2047; int srccol = (ci & 3)*512 + (ci >> 2);   // col' = u*4+g  <- g*512+u
  for (int kk = 0; kk < 80; kk++){
    int row = kk*4 + rr;
    float v = (row < 300) ? W[(size_t)row*2048 + srccol] : 0.f;
    lds[row][cl] = f2bf(v);
  }
  __syncthreads();
  int cw = tid >> 2, kc = tid & 3;
  #pragma unroll
  for (int j = 0; j < 10; j++){
    u16x8 v;
    #pragma unroll
    for (int e = 0; e < 8; e++) v[e] = lds[kc*80 + j*8 + e][cw];
    *(u16x8*)&wpt[(size_t)(c0+cw)*EP + kc*80 + j*8] = v;
  }
  if (tid < 64){
    int ci2 = (c0 + tid) & 2047; int sc = (ci2 & 3)*512 + (ci2 >> 2);
    bias[c0 + tid] = (dir ? bbv : bfv)[sc];
  }
}

// ---------------------------------------------------------------- prep: U -> [col'][K] bf16
__global__ __launch_bounds__(256) void k_prep_ut(const float* __restrict__ Uf, const float* __restrict__ Ub,
                                                 u16* __restrict__ upt){
  __shared__ u16 lds[512][32];
  int bid = blockIdx.x, tid = threadIdx.x;   // 128 wgs
  int cg0 = bid*32; int dir = cg0 >> 11;
  const float* U = dir ? Ub : Uf;
  int cl = tid & 31, rr = tid >> 5;
  int ci = (cg0 + cl) & 2047; int srccol = (ci & 3)*512 + (ci >> 2);
  for (int kk = 0; kk < 64; kk++){
    int row = kk*8 + rr;
    lds[row][cl] = f2bf(U[(size_t)row*2048 + srccol]);
  }
  __syncthreads();
  int cw = tid >> 3, kc = tid & 7;
  #pragma unroll
  for (int j = 0; j < 8; j++){
    u16x8 v;
    #pragma unroll
    for (int e = 0; e < 8; e++) v[e] = lds[kc*64 + j*8 + e][cw];
    *(u16x8*)&upt[(size_t)(cg0+cw)*512 + kc*64 + j*8] = v;
  }
}

// ---------------------------------------------------------------- prep: mask + tagged h image init
__global__ __launch_bounds__(256) void k_prep_misc(const int* __restrict__ x,
                                                   const float* __restrict__ h0f, const float* __restrict__ h0b,
                                                   u32* __restrict__ maskb, u32* __restrict__ himg){
  int bid = blockIdx.x, tid = threadIdx.x;
  if (bid == 256){
    int b = tid >> 3, w = tid & 7;
    u32 m = 0;
    for (int i = 0; i < 32; i++){ int t = w*32 + i; m |= (u32)(x[b*256 + t] != 0) << i; }
    maskb[b*8 + w] = m;
    return;
  }
  int idx = bid*256 + tid;                      // 0 .. 65535
  int dir = idx >> 15, rem = idx & 32767, par = rem >> 14, di = rem & 16383;
  u32* img = himg + (size_t)dir*32768 + (size_t)par*16384;
  if (par == 0){
    img[di] = 0x0000DEADu;                      // invalid tag (never matches 0..254 / 0xFFFF)
  } else {
    int j = di & 7, lane2 = (di >> 3) & 63, ks = (di >> 9) & 15, mt = di >> 13;
    int b = mt*16 + (lane2 & 15), ug = ks*32 + (lane2 >> 4)*8 + j;
    const float* h0 = dir ? h0b : h0f;
    img[di] = ((u32)f2bf(h0[b*512 + ug]) << 16) | 0xFFFFu;   // h_{-1}, tag -1
  }
}

// ---------------------------------------------------------------- input GEMM: xW+b (bf16 MFMA)
__global__ __launch_bounds__(512) void k_ingemm(const u16* __restrict__ aemb, const u16* __restrict__ wpt,
                                                const float* __restrict__ bias, u16* __restrict__ xw){
  int bx = blockIdx.x, by = blockIdx.y;        // 64 x 64
  int tid = threadIdx.x, lane = tid & 63, wv = tid >> 6;
  int m0 = bx*128 + wv*16;
  u16x8 afr[10];
  const u16* ap = aemb + (size_t)(m0 + (lane & 15))*EP + ((lane >> 4)*8);
  #pragma unroll
  for (int ks = 0; ks < 10; ks++) afr[ks] = *(const u16x8*)(ap + ks*32);
  #pragma unroll
  for (int n = 0; n < 4; n++){
    int colp = by*64 + n*16 + (lane & 15);
    const u16* bp = wpt + (size_t)colp*EP + ((lane >> 4)*8);
    f32x4 acc = {0.f, 0.f, 0.f, 0.f};
    #pragma unroll
    for (int ks = 0; ks < 10; ks++){
      bf16x8 bfr = __builtin_bit_cast(bf16x8, *(const u16x8*)(bp + ks*32));
      acc = __builtin_amdgcn_mfma_f32_16x16x32_bf16(__builtin_bit_cast(bf16x8, afr[ks]), bfr, acc, 0, 0, 0);
    }
    float bv = bias[colp];
    #pragma unroll
    for (int v = 0; v < 4; v++){
      int m = m0 + (lane >> 4)*4 + v;          // C/D: col=lane&15, row=(lane>>4)*4+reg  [m89]
      xw[(size_t)m*NC + colp] = f2bf(acc[v] + bv);
    }
  }
}

// ---------------------------------------------------------------- persistent recurrence
__global__ __launch_bounds__(512) void k_recur(const u16* __restrict__ xw, const u16* __restrict__ upt,
                                               const u32* __restrict__ maskb, u32* __restrict__ himg,
                                               const float* __restrict__ c0f, const float* __restrict__ c0b,
                                               const float* __restrict__ h0f, const float* __restrict__ h0b,
                                               float* __restrict__ out){
  int bid = blockIdx.x;                        // 64 wgs
  int dir = bid & 1, r = bid >> 1;             // direction, rank in group (0..31)
  int tid = threadIdx.x, lane = tid & 63, wv = tid >> 6;
  int nw = wv & 3, kh = wv >> 2;               // wave's N-tile (of 4) and K-half

  __shared__ u16   astage[2][16384];           // double-buffered bf16 frag image (64 KB)
  __shared__ float zbuf[2][32][64];            // [khalf][b][local col], 16 KB
  __shared__ u32   mk[32][8];

  // U-slice as persistent B-fragments in registers (col = r*64 + nw*16 + lane&15)
  bf16x8 bfr[8];
  {
    const u16* ub = upt + ((size_t)dir*2048 + r*64 + nw*16 + (lane & 15))*512 + ((lane >> 4)*8);
    #pragma unroll
    for (int i = 0; i < 8; i++){ int ks = kh*8 + i; bfr[i] = __builtin_bit_cast(bf16x8, *(const u16x8*)(ub + ks*32)); }
  }
  int b = tid >> 4, u = tid & 15, ug = r*16 + u;
  float c_reg = (dir ? c0b : c0f)[b*512 + ug];
  float h_reg = (dir ? h0b : h0f)[b*512 + ug];
  if (tid < 256) mk[tid >> 3][tid & 7] = maskb[tid];
  __syncthreads();

  u32* img = himg + (size_t)dir*32768;
  int ks2 = r >> 1, qv = ((r & 1) << 1) | (u >> 3);
  // publish dword index for this thread's h value
  size_t dpub = (((size_t)(b >> 4)*16 + ks2)*64 + (size_t)(qv*16 + (b & 15)))*8 + (u & 7);

  int t0 = dir ? 255 : 0;
  u16x4 pref = *(const u16x4*)(xw + (size_t)(t0*32 + b)*NC + dir*2048 + r*64 + u*4);

  for (int s = 0; s < 256; ++s){
    int t = dir ? 255 - s : s;
    int sn = (s < 255) ? s + 1 : s;
    int tn = dir ? 255 - sn : sn;
    u16x4 nxt = *(const u16x4*)(xw + (size_t)(tn*32 + b)*NC + dir*2048 + r*64 + u*4);

    // ---- stage + verify: 8 tagged 16B chunks/thread (full 64KB image), retry
    u32 tg = (u32)((s - 1) & 0xFFFF);
    int pr = (s + 1) & 1;
    const char* gsrc = (const char*)(img + (size_t)pr*16384) + (size_t)tid*16;
    u32x4 v0, v1, v2, v3, v4, v5, v6, v7;
    #define LD(i) asm volatile("global_load_dwordx4 %0, %1, off sc0 sc1" : "=v"(v##i) : "v"(gsrc + i*8192))
    LD(0); LD(1); LD(2); LD(3); LD(4); LD(5); LD(6); LD(7);
    u32 pend = 255u;
    for (;;){
      asm volatile("s_waitcnt vmcnt(0)" ::: "memory");
      __builtin_amdgcn_sched_barrier(0);
      #define CK(i) if (pend & (1u << i)){ \
        if ((((v##i.x ^ tg) | (v##i.y ^ tg) | (v##i.z ^ tg) | (v##i.w ^ tg)) & 0xFFFFu) == 0u){ \
          u16x4 p; p[0] = (u16)(v##i.x >> 16); p[1] = (u16)(v##i.y >> 16); \
                   p[2] = (u16)(v##i.z >> 16); p[3] = (u16)(v##i.w >> 16); \
          *(u16x4*)((char*)&astage[pr][0] + (size_t)tid*8 + i*4096) = p; \
          pend &= ~(1u << i); \
        } else { LD(i); } }
      CK(0); CK(1); CK(2); CK(3); CK(4); CK(5); CK(6); CK(7);
      #undef CK
      if (!pend) break;
    }
    #undef LD
    __syncthreads();                            // (B) astage[pr] ready

    // ---- z = h_{s-1} @ U from LDS frags
    f32x4 acc0 = {0.f,0.f,0.f,0.f}, acc1 = {0.f,0.f,0.f,0.f};
    {
      const u16* ab = &astage[pr][0] + lane*8;
      #pragma unroll
      for (int i = 0; i < 8; i++){
        int ks = kh*8 + i;
        bf16x8 a0 = __builtin_bit_cast(bf16x8, *(const u16x8*)(ab + (size_t)ks*512));
        bf16x8 a1 = __builtin_bit_cast(bf16x8, *(const u16x8*)(ab + (size_t)(16 + ks)*512));
        acc0 = __builtin_amdgcn_mfma_f32_16x16x32_bf16(a0, bfr[i], acc0, 0, 0, 0);
        acc1 = __builtin_amdgcn_mfma_f32_16x16x32_bf16(a1, bfr[i], acc1, 0, 0, 0);
      }
      int row0 = (lane >> 4)*4, cc = nw*16 + (lane & 15);
      #pragma unroll
      for (int v = 0; v < 4; v++){
        zbuf[kh][row0 + v][cc]      = acc0[v];
        zbuf[kh][16 + row0 + v][cc] = acc1[v];
      }
    }
    __syncthreads();                            // (C) zbuf ready

    // ---- gate stage: thread (b,u)
    f32x4 za = *(const f32x4*)&zbuf[0][b][u*4];
    f32x4 zc = *(const f32x4*)&zbuf[1][b][u*4];
    float zi = za[0] + zc[0] + bf2f(pref[0]);
    float zf = za[1] + zc[1] + bf2f(pref[1]);
    float zg = za[2] + zc[2] + bf2f(pref[2]);
    float zo = za[3] + zc[3] + bf2f(pref[3]);
    float gi = sigm(zi), gf = sigm(zf), gg = tanh_(zg), go = sigm(zo);
    float cn = gf*c_reg + gi*gg;
    float hn = go*tanh_(cn);
    if ((mk[b][t >> 5] >> (t & 31)) & 1){ c_reg = cn; h_reg = hn; }
    float hc = h_reg;

    // ---- publish immediately: one tagged dword per thread (fire-and-forget)
    if (s < 255){
      u32 dw = ((u32)f2bf(hc) << 16) | (u32)s;
      u32* gdst = img + (size_t)(s & 1)*16384 + dpub;
      asm volatile("global_store_dword %0, %1, off sc0 sc1" :: "v"(gdst), "v"(dw) : "memory");
    }

    // ---- out-stores off the critical path
    out[(size_t)(b*256 + t)*1024 + dir*512 + ug] = hc;
    if (s == 255){
      out[8388608 + dir*16384 + b*512 + ug] = hc;                 // h_f / h_b
      out[8388608 + 32768 + dir*16384 + b*512 + ug] = c_reg;      // c_f / c_b
    }
    pref = nxt;
  }
}

// ----------------------------------------------------------------------------
extern "C" void kernel_launch(void* const* d_in, const int* in_sizes, int n_in,
                              void* d_out, int out_size, void* d_ws, size_t ws_size,
                              hipStream_t stream){
  const int*   x   = (const int*)  d_in[0];
  const float* h0f = (const float*)d_in[1];
  const float* c0f = (const float*)d_in[2];
  const float* h0b = (const float*)d_in[3];
  const float* c0b = (const float*)d_in[4];
  const float* emb = (const float*)d_in[5];
  const float* Wf  = (const float*)d_in[6];
  const float* Uf  = (const float*)d_in[7];
  const float* bfv = (const float*)d_in[8];
  const float* Wb  = (const float*)d_in[9];
  const float* Ub  = (const float*)d_in[10];
  const float* bbv = (const float*)d_in[11];
  float* out = (float*)d_out;

  char* w = (char*)d_ws;
  u16*   aemb = (u16*)(w + OFF_AEMB);
  u16*   wpt  = (u16*)(w + OFF_WPT);
  float* bias = (float*)(w + OFF_BIAS);
  u16*   upt  = (u16*)(w + OFF_UPT);
  u32*   mskb = (u32*)(w + OFF_MASK);
  u32*   himg = (u32*)(w + OFF_HIMG);
  u16*   xw   = (u16*)(w + OFF_XW);

  k_prep_aemb<<<dim3(8192),  dim3(320), 0, stream>>>(x, emb, aemb);
  k_prep_wt  <<<dim3(64),    dim3(256), 0, stream>>>(Wf, Wb, bfv, bbv, wpt, bias);
  k_prep_ut  <<<dim3(128),   dim3(256), 0, stream>>>(Uf, Ub, upt);
  k_prep_misc<<<dim3(257),   dim3(256), 0, stream>>>(x, h0f, h0b, mskb, himg);
  k_ingemm   <<<dim3(64,64), dim3(512), 0, stream>>>(aemb, wpt, bias, xw);
  k_recur    <<<dim3(64),    dim3(512), 0, stream>>>(xw, upt, mskb, himg,
                                                     c0f, c0b, h0f, h0b, out);
}